// Round 1
// 404.630 us; speedup vs baseline: 1.0075x; 1.0075x over previous
//
#include <hip/hip_runtime.h>
#include <math.h>

// Problem constants (match reference)
#define N_NEU   8192
#define IN_SZ   512
#define OUT_SZ  512
#define N4      (N_NEU / 4)          // 2048 float4 col-quads per row of W_in/synapses
#define OUT4    (OUT_SZ / 4)         // 128 quads per W_out row
#define KPB     128                  // k-rows per K1 block
#define SYN_TILES (N_NEU / KPB)      // 64
#define WIN_TILES (IN_SZ / KPB)      // 4
#define TILES     (SYN_TILES + WIN_TILES)  // 68
#define K2_KPB  64                   // k-rows per K2 out-gemv tile
#define OTILES  (N_NEU / K2_KPB)     // 128
constexpr float TAU_INV = 0.1f;
constexpr float G_GAIN  = 1.5f;

// ---------------------------------------------------------------------------
// K0: zero out[0:8704]. out[512:8704] is K1's atomic accumulator (drive sums),
//     out[0:512] is K2's atomic accumulator (final output). 34*256 = 8704.
// ---------------------------------------------------------------------------
__global__ __launch_bounds__(256)
void zero_kernel(float* __restrict__ out) {
    out[blockIdx.x * 256 + threadIdx.x] = 0.0f;
}

// ---------------------------------------------------------------------------
// K1: split-K GEMV, NO workspace. Each block owns one (col-stripe, k-tile):
//     acc[1024 cols] = sum_{k in tile} xs[k] * M[k][cols], then
//     atomicAdd into out[512 + col]. xs = G*tanh(pot) for synapse tiles,
//     inputs for W_in tiles. 68*8192 = 557K fp32 atomics total (68-way/addr).
// grid = (8, 68), block = 256
// ---------------------------------------------------------------------------
__global__ __launch_bounds__(256)
void accum_kernel(const float* __restrict__ pot,
                  const float* __restrict__ inputs,
                  const float* __restrict__ synapses,
                  const float* __restrict__ W_in,
                  float* __restrict__ out) {
    __shared__ float xs[KPB];
    const int bx = blockIdx.x, by = blockIdx.y;
    const int tid = threadIdx.x;
    const float4* M;
    int k0;
    if (by < SYN_TILES) {                     // synapses tile
        k0 = by * KPB;
        M  = (const float4*)synapses;
        if (tid < KPB) xs[tid] = G_GAIN * tanhf(pot[k0 + tid]);
    } else {                                  // W_in tile
        k0 = (by - SYN_TILES) * KPB;
        M  = (const float4*)W_in;
        if (tid < KPB) xs[tid] = inputs[k0 + tid];
    }
    __syncthreads();

    const int col4 = bx * 256 + tid;
    const float4* Mp = M + (size_t)k0 * N4 + col4;

    float4 acc = make_float4(0.f, 0.f, 0.f, 0.f);
#pragma unroll 8
    for (int i = 0; i < KPB; ++i) {
        float  s = xs[i];
        float4 m = Mp[(size_t)i * N4];
        acc.x = fmaf(s, m.x, acc.x);
        acc.y = fmaf(s, m.y, acc.y);
        acc.z = fmaf(s, m.z, acc.z);
        acc.w = fmaf(s, m.w, acc.w);
    }
    float* op = out + OUT_SZ + (size_t)col4 * 4;
    atomicAdd(op + 0, acc.x);
    atomicAdd(op + 1, acc.y);
    atomicAdd(op + 2, acc.z);
    atomicAdd(op + 3, acc.w);
}

// ---------------------------------------------------------------------------
// K2: 128 blocks, 64 rows each. Read accumulated drive s = out[512+j]
//     (one load — no partial-reduction loop), pot_new in-place,
//     gen = tanh(pot_new), 64-row W_out gemv slice, atomics into out[0:512].
//     Row range [k0, k0+64) is owned exclusively by block b -> in-place safe.
// block = 128
// ---------------------------------------------------------------------------
__global__ __launch_bounds__(128)
void finish_kernel(const float* __restrict__ pot,
                   const float* __restrict__ W_out,
                   float* __restrict__ out) {
    __shared__ float xs[K2_KPB];
    const int b = blockIdx.x;
    const int t = threadIdx.x;
    const int k0 = b * K2_KPB;

    if (t < K2_KPB) {
        float s  = out[OUT_SZ + k0 + t];      // accumulated G*(r@syn) + drive
        float p  = pot[k0 + t];
        float pn = p + (s - p) * TAU_INV;
        out[OUT_SZ + k0 + t] = pn;            // pot_new (exclusive rows)
        xs[t] = tanhf(pn);
    }
    __syncthreads();

    const float4* Wp = (const float4*)W_out + (size_t)k0 * OUT4 + t;
    float4 acc = make_float4(0.f, 0.f, 0.f, 0.f);
#pragma unroll 8
    for (int i = 0; i < K2_KPB; ++i) {
        float  sx = xs[i];
        float4 m  = Wp[(size_t)i * OUT4];
        acc.x = fmaf(sx, m.x, acc.x);
        acc.y = fmaf(sx, m.y, acc.y);
        acc.z = fmaf(sx, m.z, acc.z);
        acc.w = fmaf(sx, m.w, acc.w);
    }
    float* op = out + (size_t)t * 4;
    atomicAdd(op + 0, acc.x);
    atomicAdd(op + 1, acc.y);
    atomicAdd(op + 2, acc.z);
    atomicAdd(op + 3, acc.w);
}

// ---------------------------------------------------------------------------
extern "C" void kernel_launch(void* const* d_in, const int* in_sizes, int n_in,
                              void* d_out, int out_size, void* d_ws, size_t ws_size,
                              hipStream_t stream) {
    const float* inputs   = (const float*)d_in[0];   // [512]
    const float* pot      = (const float*)d_in[1];   // [8192]
    const float* W_in     = (const float*)d_in[2];   // [512, 8192]
    const float* synapses = (const float*)d_in[3];   // [8192, 8192]
    const float* W_out    = (const float*)d_in[4];   // [8192, 512]

    float* out = (float*)d_out;          // [0:512] output, [512:8704] pot_new
    (void)d_ws; (void)ws_size;           // workspace intentionally UNUSED

    // K0: zero both atomic accumulators (8704 floats)
    zero_kernel<<<dim3((OUT_SZ + N_NEU) / 256), dim3(256), 0, stream>>>(out);

    // K1: 8 col-stripes x (64 synapse + 4 W_in) k-tiles, atomics into out[512:]
    accum_kernel<<<dim3(8, TILES), dim3(256), 0, stream>>>(
        pot, inputs, synapses, W_in, out);

    // K2: 128 tiles of 64 rows: pot_new + out-gemv with atomics into out[0:512]
    finish_kernel<<<dim3(OTILES), dim3(128), 0, stream>>>(pot, W_out, out);
}